// Round 1
// baseline (1186.256 us; speedup 1.0000x reference)
//
#include <hip/hip_runtime.h>

// ---------------------------------------------------------------------------
// DeepSeek MoE forward on MI355X (gfx950).
// Pipeline: zero_meta -> router -> finalize(meta+aux) -> gather ->
//   [shared: conv W, GEMM1 dual-B (silu fuse), conv Wd, GEMM2 plain-store] ->
//   groups: [conv gate/up bf16, GEMM1 routed] -> [conv down, GEMM2 atomicAdd]
// GEMMs: m97 recipe: 128x128 tile, BK=32, mfma_f32_16x16x32_bf16,
//        global_load_lds width=16, BT layout (weights are [N,K] row-major).
// R1: XCD-aware bijective block swizzle (T1/m204) + y-stripe decomposition on
//     all GEMMs. Rationale: linear ids round-robin across 8 non-coherent XCD
//     L2s, so the 8 (GEMM2) / 32 (GEMM1) x-tiles sharing one A panel each
//     fetched it into a different L2 -> ~3x HBM over-fetch (FETCH 425MB vs
//     143MB ideal on routed GEMM2). Chunked remap keeps an XCD's A panels
//     L2-resident; B streams once per stripe.
// ---------------------------------------------------------------------------

typedef unsigned short u16;
typedef unsigned int u32;

typedef short bf16x8 __attribute__((ext_vector_type(8)));
typedef float f32x4 __attribute__((ext_vector_type(4)));

#define GLD16(g, l)                                                            \
  __builtin_amdgcn_global_load_lds(                                            \
      (const __attribute__((address_space(1))) void*)(g),                      \
      (__attribute__((address_space(3))) void*)(l), 16, 0, 0)

__device__ __forceinline__ u32 rne16(float f) {
  u32 u = __float_as_uint(f);
  return (u + 0x7fffu + ((u >> 16) & 1u)) >> 16;
}
__device__ __forceinline__ u16 bf16of(float f) { return (u16)rne16(f); }
__device__ __forceinline__ u32 pk2(float lo, float hi) {
  return rne16(lo) | (rne16(hi) << 16);
}

// Bijective XCD-chunk remap (m204): block lin%8 runs on XCD lin%8; give each
// XCD a contiguous range of logical tile ids so neighbor tiles share its L2.
__device__ __forceinline__ int xcd_remap() {
  int lin = blockIdx.x + gridDim.x * (blockIdx.y + gridDim.y * blockIdx.z);
  int nwg = gridDim.x * gridDim.y * gridDim.z;
  int xcd = lin & 7, idx = lin >> 3;
  int q = nwg >> 3, r = nwg & 7;
  int base = xcd < r ? xcd * (q + 1) : r * (q + 1) + (xcd - r) * q;
  return base + idx;
}

// ---------------- meta layout (int* meta at ws+0) ----------------
// [0..7]  cnt[e]      [8..15] padded[e]    [16..24] base[e] (base[8]=total)
// float at meta+32 : z-loss accumulator

__global__ void zero_meta_kernel(int* __restrict__ meta) {
  int t = threadIdx.x;
  if (t < 8) meta[t] = 0;
  if (t == 8) ((float*)(meta + 32))[0] = 0.0f;
}

// one wave (64 threads) per token
__global__ void router_kernel(const float* __restrict__ x,
                              const float* __restrict__ rw,
                              u16* __restrict__ xb, int* __restrict__ tlist,
                              float* __restrict__ gwv, int* __restrict__ meta) {
  int tok = blockIdx.x;
  int lane = threadIdx.x;
  const float* xr = x + (size_t)tok * 1024;
  float acc[8] = {0.f, 0.f, 0.f, 0.f, 0.f, 0.f, 0.f, 0.f};
#pragma unroll
  for (int c = 0; c < 16; c++) {
    float xv = xr[lane + 64 * c];
    xb[(size_t)tok * 1024 + lane + 64 * c] = bf16of(xv);
#pragma unroll
    for (int e = 0; e < 8; e++) acc[e] += xv * rw[e * 1024 + lane + 64 * c];
  }
#pragma unroll
  for (int e = 0; e < 8; e++) {
    float v = acc[e];
    for (int m = 32; m > 0; m >>= 1) v += __shfl_xor(v, m, 64);
    acc[e] = v;
  }
  if (lane == 0) {
    float z = 0.f;
#pragma unroll
    for (int e = 0; e < 8; e++) z += acc[e] * acc[e];
    atomicAdd((float*)(meta + 32), z);
    int i1 = 0;
    float b1 = acc[0];
#pragma unroll
    for (int e = 1; e < 8; e++)
      if (acc[e] > b1) { b1 = acc[e]; i1 = e; }
    int i2 = -1;
    float b2 = -3.0e38f;
#pragma unroll
    for (int e = 0; e < 8; e++)
      if (e != i1 && acc[e] > b2) { b2 = acc[e]; i2 = e; }
    float w1 = 1.0f / (1.0f + __expf(b2 - b1));  // = p1/(p1+p2)
    float w2 = 1.0f - w1;
    int s1 = atomicAdd(&meta[i1], 1);
    tlist[i1 * 4096 + s1] = tok;
    gwv[i1 * 4096 + s1] = w1;
    int s2 = atomicAdd(&meta[i2], 1);
    tlist[i2 * 4096 + s2] = tok;
    gwv[i2 * 4096 + s2] = w2;
  }
}

__global__ void finalize_kernel(int* __restrict__ meta, float* __restrict__ out) {
  if (threadIdx.x == 0) {
    int* basep = meta + 16;
    int base = 0;
    float lb = 0.f;
    const float invsum = 1.0f / 12288.0f;  // sum loads = 8192 + 4096
    const float ideal = 1.0f / 9.0f;
    for (int e = 0; e < 8; e++) {
      int c = meta[e];
      int p = (c + 127) & ~127;
      meta[8 + e] = p;
      basep[e] = base;
      base += p;
      float d = (float)c * invsum - ideal;
      lb += d * d;
    }
    basep[8] = base;
    float dsh = 4096.0f * invsum - ideal;
    lb += dsh * dsh;
    lb *= (1.0f / 9.0f);
    float z = ((float*)(meta + 32))[0] * (1.0f / 4096.0f);
    out[4194304] = 0.01f * lb + 0.01f * z;  // total_aux_loss
  }
}

// one block (128 thr) per gathered row; zero pads
__global__ void gather_kernel(const u16* __restrict__ xb, u16* __restrict__ Ag,
                              const int* __restrict__ tlist,
                              const int* __restrict__ meta) {
  int r = blockIdx.x;
  int t = threadIdx.x;
  const int* base = meta + 16;
  int total = base[8];
  uint4 val = make_uint4(0u, 0u, 0u, 0u);
  if (r < total) {
    int e = 0;
#pragma unroll
    for (int q = 1; q < 8; q++)
      if (r >= base[q]) e = q;
    int s = r - base[e];
    if (s < meta[e]) {
      int tok = tlist[e * 4096 + s];
      val = *((const uint4*)(xb + (size_t)tok * 1024) + t);
    }
  }
  *((uint4*)(Ag + (size_t)r * 1024) + t) = val;
}

// fp32 -> bf16 (RNE), 8 elems/thread
__global__ void conv_kernel(const float* __restrict__ src, u16* __restrict__ dst,
                            int n8) {
  int i = blockIdx.x * 256 + threadIdx.x;
  if (i >= n8) return;
  const float4* s = (const float4*)src + (size_t)i * 2;
  float4 a = s[0], b = s[1];
  uint4 o;
  o.x = pk2(a.x, a.y);
  o.y = pk2(a.z, a.w);
  o.z = pk2(b.x, b.y);
  o.w = pk2(b.z, b.w);
  ((uint4*)dst)[i] = o;
}

// ---------------- GEMM1: h = silu(A@Wg^T) * (A@Wu^T), bf16 out -------------
// A [rows,1024] bf16, Wg/Wu [elocal][4096][1024] bf16, Hout [rows,4096] bf16
__global__ __launch_bounds__(256, 2) void gemm1_kernel(
    const u16* __restrict__ A, const u16* __restrict__ Wg,
    const u16* __restrict__ Wu, u16* __restrict__ Hout,
    const int* __restrict__ meta, int e_lo, int e_hi) {
  __shared__ u16 sA[128 * 32];
  __shared__ u16 sBg[128 * 32];
  __shared__ u16 sBu[128 * 32];

  // XCD swizzle + stripe-8 decomposition (stripe ~= one expert's y-panels):
  // within an XCD chunk, 8 A panels (2 MB) stay L2-resident while B tiles
  // stream through once per stripe.
  int wg = xcd_remap();
  int per = 8 * gridDim.x;
  int ins = wg % per;
  int by = (wg / per) * 8 + (ins & 7);
  int bx = ins >> 3;

  int r0, elocal;
  if (meta != nullptr) {
    const int* base = meta + 16;
    r0 = base[e_lo] + by * 128;
    if (r0 >= base[e_hi]) return;
    int e = e_lo;
#pragma unroll
    for (int q = 1; q < 8; q++)
      if (q > e_lo && q < e_hi && r0 >= base[q]) e = q;
    elocal = e - e_lo;
  } else {
    r0 = by * 128;
    elocal = 0;
  }
  int n0 = bx * 128;
  int t = threadIdx.x;

  const u16* aP = A + (size_t)(r0 + (t >> 2)) * 1024 + (t & 3) * 8;
  const u16* gP =
      Wg + (size_t)elocal * 4194304 + (size_t)(n0 + (t >> 2)) * 1024 + (t & 3) * 8;
  const u16* uP =
      Wu + (size_t)elocal * 4194304 + (size_t)(n0 + (t >> 2)) * 1024 + (t & 3) * 8;
  u16* aD = sA + t * 8;
  u16* gD = sBg + t * 8;
  u16* uD = sBu + t * 8;

  int lane = t & 63, wid = t >> 6;
  int wm = wid >> 1, wn = wid & 1;
  int l15 = lane & 15, quad = lane >> 4;
  const u16* aR = sA + (wm * 64 + l15) * 32 + quad * 8;
  const u16* gR = sBg + (wn * 64 + l15) * 32 + quad * 8;
  const u16* uR = sBu + (wn * 64 + l15) * 32 + quad * 8;

  f32x4 accg[4][4] = {};
  f32x4 accu[4][4] = {};

#pragma unroll 1
  for (int kk = 0; kk < 32; kk++) {
    if (kk) __syncthreads();
    GLD16(aP, aD);
    GLD16(aP + 64 * 1024, aD + 2048);
    GLD16(gP, gD);
    GLD16(gP + 64 * 1024, gD + 2048);
    GLD16(uP, uD);
    GLD16(uP + 64 * 1024, uD + 2048);
    aP += 32;
    gP += 32;
    uP += 32;
    __syncthreads();

    bf16x8 af[4];
#pragma unroll
    for (int i = 0; i < 4; i++) af[i] = *(const bf16x8*)(aR + i * 512);
#pragma unroll
    for (int j = 0; j < 4; j++) {
      bf16x8 bg = *(const bf16x8*)(gR + j * 512);
      bf16x8 bu = *(const bf16x8*)(uR + j * 512);
#pragma unroll
      for (int i = 0; i < 4; i++) {
        accg[i][j] =
            __builtin_amdgcn_mfma_f32_16x16x32_bf16(af[i], bg, accg[i][j], 0, 0, 0);
        accu[i][j] =
            __builtin_amdgcn_mfma_f32_16x16x32_bf16(af[i], bu, accu[i][j], 0, 0, 0);
      }
    }
  }

  // epilogue: h = silu(g)*u ; C/D map: row=(lane>>4)*4+reg, col=lane&15
#pragma unroll
  for (int i = 0; i < 4; i++) {
    int row = r0 + wm * 64 + i * 16 + quad * 4;
#pragma unroll
    for (int r = 0; r < 4; r++) {
      u16* hrow = Hout + (size_t)(row + r) * 4096 + n0 + wn * 64 + l15;
#pragma unroll
      for (int j = 0; j < 4; j++) {
        float g = accg[i][j][r];
        float u = accu[i][j][r];
        float s = g / (1.0f + __expf(-g));
        hrow[j * 16] = bf16of(s * u);
      }
    }
  }
}

// ---------------- GEMM2: out[token] (+)= w * (A@Wd^T) ----------------------
// A [rows,4096] bf16, Wd [elocal][1024][4096] bf16, out [4096,1024] fp32
__global__ __launch_bounds__(256, 2) void gemm2_kernel(
    const u16* __restrict__ A, const u16* __restrict__ Wd,
    float* __restrict__ out, const int* __restrict__ meta, int e_lo, int e_hi,
    const int* __restrict__ tlist, const float* __restrict__ gwv, int ksteps) {
  __shared__ u16 sA[128 * 32];
  __shared__ u16 sB[128 * 32];

  // XCD swizzle + stripe-4 decomposition: 4 A panels (2 MB) L2-resident,
  // B tiles stream once per stripe.
  int wg = xcd_remap();
  int gxy = gridDim.x * gridDim.y;
  int bz = wg / gxy;
  int w2 = wg - bz * gxy;
  int per = 4 * gridDim.x;
  int ins = w2 % per;
  int by = (w2 / per) * 4 + (ins & 3);
  int bx = ins >> 2;

  int r0, e;
  if (meta != nullptr) {
    const int* base = meta + 16;
    r0 = base[e_lo] + by * 128;
    if (r0 >= base[e_hi]) return;
    e = e_lo;
#pragma unroll
    for (int q = 1; q < 8; q++)
      if (q > e_lo && q < e_hi && r0 >= base[q]) e = q;
  } else {
    r0 = by * 128;
    e = e_lo;
  }
  int elocal = e - e_lo;
  int n0 = bx * 128;
  int k0 = bz * ksteps;
  int t = threadIdx.x;

  const u16* aP =
      A + (size_t)(r0 + (t >> 2)) * 4096 + (size_t)k0 * 32 + (t & 3) * 8;
  const u16* bP = Wd + (size_t)elocal * 4194304 +
                  (size_t)(n0 + (t >> 2)) * 4096 + (size_t)k0 * 32 + (t & 3) * 8;
  u16* aD = sA + t * 8;
  u16* bD = sB + t * 8;

  int lane = t & 63, wid = t >> 6;
  int wm = wid >> 1, wn = wid & 1;
  int l15 = lane & 15, quad = lane >> 4;
  const u16* aR = sA + (wm * 64 + l15) * 32 + quad * 8;
  const u16* bR = sB + (wn * 64 + l15) * 32 + quad * 8;

  f32x4 acc[4][4] = {};

#pragma unroll 1
  for (int kk = 0; kk < ksteps; kk++) {
    if (kk) __syncthreads();
    GLD16(aP, aD);
    GLD16(aP + 64 * 4096, aD + 2048);
    GLD16(bP, bD);
    GLD16(bP + 64 * 4096, bD + 2048);
    aP += 32;
    bP += 32;
    __syncthreads();

    bf16x8 af[4];
#pragma unroll
    for (int i = 0; i < 4; i++) af[i] = *(const bf16x8*)(aR + i * 512);
#pragma unroll
    for (int j = 0; j < 4; j++) {
      bf16x8 bb = *(const bf16x8*)(bR + j * 512);
#pragma unroll
      for (int i = 0; i < 4; i++)
        acc[i][j] =
            __builtin_amdgcn_mfma_f32_16x16x32_bf16(af[i], bb, acc[i][j], 0, 0, 0);
    }
  }

  if (meta != nullptr) {
    int cnt_e = meta[e];
    int base_e = (meta + 16)[e];
#pragma unroll
    for (int i = 0; i < 4; i++) {
#pragma unroll
      for (int r = 0; r < 4; r++) {
        int s = r0 - base_e + wm * 64 + i * 16 + quad * 4 + r;
        if (s < cnt_e) {
          int tok = tlist[e * 4096 + s];
          float w = gwv[e * 4096 + s];
          float* orow = out + (size_t)tok * 1024 + n0 + wn * 64 + l15;
#pragma unroll
          for (int j = 0; j < 4; j++) unsafeAtomicAdd(orow + j * 16, w * acc[i][j][r]);
        }
      }
    }
  } else {
    // shared expert: plain store covers every output element exactly once
#pragma unroll
    for (int i = 0; i < 4; i++) {
#pragma unroll
      for (int r = 0; r < 4; r++) {
        int tok = r0 + wm * 64 + i * 16 + quad * 4 + r;
        float* orow = out + (size_t)tok * 1024 + n0 + wn * 64 + l15;
#pragma unroll
        for (int j = 0; j < 4; j++) orow[j * 16] = acc[i][j][r];
      }
    }
  }
}

// ---------------------------------------------------------------------------
extern "C" void kernel_launch(void* const* d_in, const int* in_sizes, int n_in,
                              void* d_out, int out_size, void* d_ws,
                              size_t ws_size, hipStream_t stream) {
  const float* x = (const float*)d_in[0];
  const float* rw = (const float*)d_in[1];
  const float* gw_ = (const float*)d_in[2];
  const float* uw_ = (const float*)d_in[3];
  const float* dw_ = (const float*)d_in[4];
  const float* sg = (const float*)d_in[5];
  const float* su = (const float*)d_in[6];
  const float* sd = (const float*)d_in[7];
  float* out = (float*)d_out;
  char* ws = (char*)d_ws;

  int* meta = (int*)(ws + 0);
  int* tlist = (int*)(ws + 256);
  float* gwv = (float*)(ws + 131328);
  u16* xb = (u16*)(ws + 262400);
  u16* Ag = (u16*)(ws + 8651008);
  u16* Hb = (u16*)(ws + 27525376);
  u16* Wbuf = (u16*)(ws + 103022848);

  // conversion-group size (experts per GEMM1 group); degrade if ws is small
  int ne = 4;
  if (ws_size < 170131712ULL) ne = 2;
  if (ws_size < 136577280ULL) ne = 1;
  const size_t EW = 4194304;  // elems per expert weight matrix

  zero_meta_kernel<<<1, 64, 0, stream>>>(meta);
  router_kernel<<<4096, 64, 0, stream>>>(x, rw, xb, tlist, gwv, meta);
  finalize_kernel<<<1, 64, 0, stream>>>(meta, out);
  gather_kernel<<<9216, 128, 0, stream>>>(xb, Ag, tlist, meta);

  // ---- shared expert (plain-store GEMM2 initializes all of out) ----
  conv_kernel<<<2048, 256, 0, stream>>>(sg, Wbuf, 524288);
  conv_kernel<<<2048, 256, 0, stream>>>(su, Wbuf + EW, 524288);
  gemm1_kernel<<<dim3(32, 32), 256, 0, stream>>>(xb, Wbuf, Wbuf + EW, Hb,
                                                 nullptr, 0, 0);
  conv_kernel<<<2048, 256, 0, stream>>>(sd, Wbuf, 524288);
  gemm2_kernel<<<dim3(8, 32, 1), 256, 0, stream>>>(Hb, Wbuf, out, nullptr, 0, 0,
                                                   tlist, gwv, 128);

  // ---- routed GEMM1 in groups of ne experts ----
  for (int g = 0; g < 8; g += ne) {
    conv_kernel<<<ne * 2048, 256, 0, stream>>>(gw_ + (size_t)g * EW, Wbuf,
                                               ne * 524288);
    conv_kernel<<<ne * 2048, 256, 0, stream>>>(uw_ + (size_t)g * EW,
                                               Wbuf + (size_t)ne * EW,
                                               ne * 524288);
    gemm1_kernel<<<dim3(32, 72), 256, 0, stream>>>(
        Ag, Wbuf, Wbuf + (size_t)ne * EW, Hb, meta, g, g + ne);
  }

  // ---- routed GEMM2 in groups of 2*ne experts, K split in 2 ----
  int ne2 = 2 * ne;
  if (ne2 > 8) ne2 = 8;
  for (int g = 0; g < 8; g += ne2) {
    conv_kernel<<<ne2 * 2048, 256, 0, stream>>>(dw_ + (size_t)g * EW, Wbuf,
                                                ne2 * 524288);
    gemm2_kernel<<<dim3(8, 72, 2), 256, 0, stream>>>(Hb, Wbuf, out, meta, g,
                                                     g + ne2, tlist, gwv, 64);
  }
}

// Round 2
// 1050.636 us; speedup vs baseline: 1.1291x; 1.1291x over previous
//
#include <hip/hip_runtime.h>

// ---------------------------------------------------------------------------
// DeepSeek MoE forward on MI355X (gfx950).
// Pipeline: zero_meta -> router -> finalize(meta+aux) -> gather ->
//   [shared: conv W, GEMM1 dual-B (silu fuse), conv Wd, GEMM2 plain-store] ->
//   groups: [conv gate/up bf16, GEMM1 routed] -> [conv down, GEMM2 atomicAdd]
// GEMMs: m97 recipe: 128x128 tile, BK=32, mfma_f32_16x16x32_bf16,
//        global_load_lds width=16, BT layout (weights are [N,K] row-major).
// R1: XCD-chunk swizzle -> FETCH dropped to ~ideal (77MB on routed GEMM1) BUT
//     remap spanned the full worst-case grid; active tiles live in the low
//     logical ids, so XCDs 4-7 got only early-exit blocks -> occupancy 8.4%,
//     latency-bound, +88us total. L2 theory right, distribution wrong.
// R2: remap over ACTIVE tiles only (nact from meta); lin >= nact exits
//     immediately (round-robin spread, harmless). Stripe-8 (G1) / stripe-4
//     (G2) in by within each XCD chunk.
// ---------------------------------------------------------------------------

typedef unsigned short u16;
typedef unsigned int u32;

typedef short bf16x8 __attribute__((ext_vector_type(8)));
typedef float f32x4 __attribute__((ext_vector_type(4)));

#define GLD16(g, l)                                                            \
  __builtin_amdgcn_global_load_lds(                                            \
      (const __attribute__((address_space(1))) void*)(g),                      \
      (__attribute__((address_space(3))) void*)(l), 16, 0, 0)

__device__ __forceinline__ u32 rne16(float f) {
  u32 u = __float_as_uint(f);
  return (u + 0x7fffu + ((u >> 16) & 1u)) >> 16;
}
__device__ __forceinline__ u16 bf16of(float f) { return (u16)rne16(f); }
__device__ __forceinline__ u32 pk2(float lo, float hi) {
  return rne16(lo) | (rne16(hi) << 16);
}

// Bijective XCD-chunk remap (m204) over the first nact logical ids.
__device__ __forceinline__ int xcd_remap_act(int lin, int nact) {
  int xcd = lin & 7, idx = lin >> 3;
  int q = nact >> 3, r = nact & 7;
  int base = xcd < r ? xcd * (q + 1) : r * (q + 1) + (xcd - r) * q;
  return base + idx;
}

// ---------------- meta layout (int* meta at ws+0) ----------------
// [0..7]  cnt[e]      [8..15] padded[e]    [16..24] base[e] (base[8]=total)
// float at meta+32 : z-loss accumulator

__global__ void zero_meta_kernel(int* __restrict__ meta) {
  int t = threadIdx.x;
  if (t < 8) meta[t] = 0;
  if (t == 8) ((float*)(meta + 32))[0] = 0.0f;
}

// one wave (64 threads) per token
__global__ void router_kernel(const float* __restrict__ x,
                              const float* __restrict__ rw,
                              u16* __restrict__ xb, int* __restrict__ tlist,
                              float* __restrict__ gwv, int* __restrict__ meta) {
  int tok = blockIdx.x;
  int lane = threadIdx.x;
  const float* xr = x + (size_t)tok * 1024;
  float acc[8] = {0.f, 0.f, 0.f, 0.f, 0.f, 0.f, 0.f, 0.f};
#pragma unroll
  for (int c = 0; c < 16; c++) {
    float xv = xr[lane + 64 * c];
    xb[(size_t)tok * 1024 + lane + 64 * c] = bf16of(xv);
#pragma unroll
    for (int e = 0; e < 8; e++) acc[e] += xv * rw[e * 1024 + lane + 64 * c];
  }
#pragma unroll
  for (int e = 0; e < 8; e++) {
    float v = acc[e];
    for (int m = 32; m > 0; m >>= 1) v += __shfl_xor(v, m, 64);
    acc[e] = v;
  }
  if (lane == 0) {
    float z = 0.f;
#pragma unroll
    for (int e = 0; e < 8; e++) z += acc[e] * acc[e];
    atomicAdd((float*)(meta + 32), z);
    int i1 = 0;
    float b1 = acc[0];
#pragma unroll
    for (int e = 1; e < 8; e++)
      if (acc[e] > b1) { b1 = acc[e]; i1 = e; }
    int i2 = -1;
    float b2 = -3.0e38f;
#pragma unroll
    for (int e = 0; e < 8; e++)
      if (e != i1 && acc[e] > b2) { b2 = acc[e]; i2 = e; }
    float w1 = 1.0f / (1.0f + __expf(b2 - b1));  // = p1/(p1+p2)
    float w2 = 1.0f - w1;
    int s1 = atomicAdd(&meta[i1], 1);
    tlist[i1 * 4096 + s1] = tok;
    gwv[i1 * 4096 + s1] = w1;
    int s2 = atomicAdd(&meta[i2], 1);
    tlist[i2 * 4096 + s2] = tok;
    gwv[i2 * 4096 + s2] = w2;
  }
}

__global__ void finalize_kernel(int* __restrict__ meta, float* __restrict__ out) {
  if (threadIdx.x == 0) {
    int* basep = meta + 16;
    int base = 0;
    float lb = 0.f;
    const float invsum = 1.0f / 12288.0f;  // sum loads = 8192 + 4096
    const float ideal = 1.0f / 9.0f;
    for (int e = 0; e < 8; e++) {
      int c = meta[e];
      int p = (c + 127) & ~127;
      meta[8 + e] = p;
      basep[e] = base;
      base += p;
      float d = (float)c * invsum - ideal;
      lb += d * d;
    }
    basep[8] = base;
    float dsh = 4096.0f * invsum - ideal;
    lb += dsh * dsh;
    lb *= (1.0f / 9.0f);
    float z = ((float*)(meta + 32))[0] * (1.0f / 4096.0f);
    out[4194304] = 0.01f * lb + 0.01f * z;  // total_aux_loss
  }
}

// one block (128 thr) per gathered row; zero pads
__global__ void gather_kernel(const u16* __restrict__ xb, u16* __restrict__ Ag,
                              const int* __restrict__ tlist,
                              const int* __restrict__ meta) {
  int r = blockIdx.x;
  int t = threadIdx.x;
  const int* base = meta + 16;
  int total = base[8];
  uint4 val = make_uint4(0u, 0u, 0u, 0u);
  if (r < total) {
    int e = 0;
#pragma unroll
    for (int q = 1; q < 8; q++)
      if (r >= base[q]) e = q;
    int s = r - base[e];
    if (s < meta[e]) {
      int tok = tlist[e * 4096 + s];
      val = *((const uint4*)(xb + (size_t)tok * 1024) + t);
    }
  }
  *((uint4*)(Ag + (size_t)r * 1024) + t) = val;
}

// fp32 -> bf16 (RNE), 8 elems/thread
__global__ void conv_kernel(const float* __restrict__ src, u16* __restrict__ dst,
                            int n8) {
  int i = blockIdx.x * 256 + threadIdx.x;
  if (i >= n8) return;
  const float4* s = (const float4*)src + (size_t)i * 2;
  float4 a = s[0], b = s[1];
  uint4 o;
  o.x = pk2(a.x, a.y);
  o.y = pk2(a.z, a.w);
  o.z = pk2(b.x, b.y);
  o.w = pk2(b.z, b.w);
  ((uint4*)dst)[i] = o;
}

// ---------------- GEMM1: h = silu(A@Wg^T) * (A@Wu^T), bf16 out -------------
// A [rows,1024] bf16, Wg/Wu [elocal][4096][1024] bf16, Hout [rows,4096] bf16
__global__ __launch_bounds__(256, 2) void gemm1_kernel(
    const u16* __restrict__ A, const u16* __restrict__ Wg,
    const u16* __restrict__ Wu, u16* __restrict__ Hout,
    const int* __restrict__ meta, int e_lo, int e_hi) {
  __shared__ u16 sA[128 * 32];
  __shared__ u16 sBg[128 * 32];
  __shared__ u16 sBu[128 * 32];

  // Active-only XCD swizzle + stripe-8 in by. nact = real y-tiles * gridDim.x;
  // inactive blocks (hw round-robin spread) exit immediately.
  const int* base = (meta != nullptr) ? (meta + 16) : nullptr;
  int gx = gridDim.x;
  int nby = (meta != nullptr) ? ((base[e_hi] - base[e_lo]) >> 7) : gridDim.y;
  int nact = nby * gx;
  int lin = blockIdx.x + gx * blockIdx.y;
  if (lin >= nact) return;
  int wg = xcd_remap_act(lin, nact);
  int per = 8 * gx;
  int nfull = nby >> 3;
  int by, bx;
  if (wg < nfull * per) {
    int stripe = wg / per, ins = wg % per;
    by = stripe * 8 + (ins & 7);
    bx = ins >> 3;
  } else {
    int rem = wg - nfull * per;
    int sh = nby - nfull * 8;
    by = nfull * 8 + rem % sh;
    bx = rem / sh;
  }

  int r0, elocal;
  if (meta != nullptr) {
    r0 = base[e_lo] + by * 128;
    int e = e_lo;
#pragma unroll
    for (int q = 1; q < 8; q++)
      if (q > e_lo && q < e_hi && r0 >= base[q]) e = q;
    elocal = e - e_lo;
  } else {
    r0 = by * 128;
    elocal = 0;
  }
  int n0 = bx * 128;
  int t = threadIdx.x;

  const u16* aP = A + (size_t)(r0 + (t >> 2)) * 1024 + (t & 3) * 8;
  const u16* gP =
      Wg + (size_t)elocal * 4194304 + (size_t)(n0 + (t >> 2)) * 1024 + (t & 3) * 8;
  const u16* uP =
      Wu + (size_t)elocal * 4194304 + (size_t)(n0 + (t >> 2)) * 1024 + (t & 3) * 8;
  u16* aD = sA + t * 8;
  u16* gD = sBg + t * 8;
  u16* uD = sBu + t * 8;

  int lane = t & 63, wid = t >> 6;
  int wm = wid >> 1, wn = wid & 1;
  int l15 = lane & 15, quad = lane >> 4;
  const u16* aR = sA + (wm * 64 + l15) * 32 + quad * 8;
  const u16* gR = sBg + (wn * 64 + l15) * 32 + quad * 8;
  const u16* uR = sBu + (wn * 64 + l15) * 32 + quad * 8;

  f32x4 accg[4][4] = {};
  f32x4 accu[4][4] = {};

#pragma unroll 1
  for (int kk = 0; kk < 32; kk++) {
    if (kk) __syncthreads();
    GLD16(aP, aD);
    GLD16(aP + 64 * 1024, aD + 2048);
    GLD16(gP, gD);
    GLD16(gP + 64 * 1024, gD + 2048);
    GLD16(uP, uD);
    GLD16(uP + 64 * 1024, uD + 2048);
    aP += 32;
    gP += 32;
    uP += 32;
    __syncthreads();

    bf16x8 af[4];
#pragma unroll
    for (int i = 0; i < 4; i++) af[i] = *(const bf16x8*)(aR + i * 512);
#pragma unroll
    for (int j = 0; j < 4; j++) {
      bf16x8 bg = *(const bf16x8*)(gR + j * 512);
      bf16x8 bu = *(const bf16x8*)(uR + j * 512);
#pragma unroll
      for (int i = 0; i < 4; i++) {
        accg[i][j] =
            __builtin_amdgcn_mfma_f32_16x16x32_bf16(af[i], bg, accg[i][j], 0, 0, 0);
        accu[i][j] =
            __builtin_amdgcn_mfma_f32_16x16x32_bf16(af[i], bu, accu[i][j], 0, 0, 0);
      }
    }
  }

  // epilogue: h = silu(g)*u ; C/D map: row=(lane>>4)*4+reg, col=lane&15
#pragma unroll
  for (int i = 0; i < 4; i++) {
    int row = r0 + wm * 64 + i * 16 + quad * 4;
#pragma unroll
    for (int r = 0; r < 4; r++) {
      u16* hrow = Hout + (size_t)(row + r) * 4096 + n0 + wn * 64 + l15;
#pragma unroll
      for (int j = 0; j < 4; j++) {
        float g = accg[i][j][r];
        float u = accu[i][j][r];
        float s = g / (1.0f + __expf(-g));
        hrow[j * 16] = bf16of(s * u);
      }
    }
  }
}

// ---------------- GEMM2: out[token] (+)= w * (A@Wd^T) ----------------------
// A [rows,4096] bf16, Wd [elocal][1024][4096] bf16, out [4096,1024] fp32
__global__ __launch_bounds__(256, 2) void gemm2_kernel(
    const u16* __restrict__ A, const u16* __restrict__ Wd,
    float* __restrict__ out, const int* __restrict__ meta, int e_lo, int e_hi,
    const int* __restrict__ tlist, const float* __restrict__ gwv, int ksteps) {
  __shared__ u16 sA[128 * 32];
  __shared__ u16 sB[128 * 32];

  // Active-only XCD swizzle + stripe-4 in by; z (K-split) derived after remap.
  const int* base = (meta != nullptr) ? (meta + 16) : nullptr;
  int gx = gridDim.x;
  int nby = (meta != nullptr) ? ((base[e_hi] - base[e_lo]) >> 7) : gridDim.y;
  int actz = nby * gx;
  int nact = actz * gridDim.z;
  int lin = blockIdx.x + gx * (blockIdx.y + gridDim.y * blockIdx.z);
  if (lin >= nact) return;
  int wg = xcd_remap_act(lin, nact);
  int bz = wg / actz;
  int w2 = wg - bz * actz;
  int per = 4 * gx;
  int nfull = nby >> 2;
  int by, bx;
  if (w2 < nfull * per) {
    int stripe = w2 / per, ins = w2 % per;
    by = stripe * 4 + (ins & 3);
    bx = ins >> 2;
  } else {
    int rem = w2 - nfull * per;
    int sh = nby - nfull * 4;
    by = nfull * 4 + rem % sh;
    bx = rem / sh;
  }

  int r0, e;
  if (meta != nullptr) {
    r0 = base[e_lo] + by * 128;
    e = e_lo;
#pragma unroll
    for (int q = 1; q < 8; q++)
      if (q > e_lo && q < e_hi && r0 >= base[q]) e = q;
  } else {
    r0 = by * 128;
    e = e_lo;
  }
  int elocal = e - e_lo;
  int n0 = bx * 128;
  int k0 = bz * ksteps;
  int t = threadIdx.x;

  const u16* aP =
      A + (size_t)(r0 + (t >> 2)) * 4096 + (size_t)k0 * 32 + (t & 3) * 8;
  const u16* bP = Wd + (size_t)elocal * 4194304 +
                  (size_t)(n0 + (t >> 2)) * 4096 + (size_t)k0 * 32 + (t & 3) * 8;
  u16* aD = sA + t * 8;
  u16* bD = sB + t * 8;

  int lane = t & 63, wid = t >> 6;
  int wm = wid >> 1, wn = wid & 1;
  int l15 = lane & 15, quad = lane >> 4;
  const u16* aR = sA + (wm * 64 + l15) * 32 + quad * 8;
  const u16* bR = sB + (wn * 64 + l15) * 32 + quad * 8;

  f32x4 acc[4][4] = {};

#pragma unroll 1
  for (int kk = 0; kk < ksteps; kk++) {
    if (kk) __syncthreads();
    GLD16(aP, aD);
    GLD16(aP + 64 * 4096, aD + 2048);
    GLD16(bP, bD);
    GLD16(bP + 64 * 4096, bD + 2048);
    aP += 32;
    bP += 32;
    __syncthreads();

    bf16x8 af[4];
#pragma unroll
    for (int i = 0; i < 4; i++) af[i] = *(const bf16x8*)(aR + i * 512);
#pragma unroll
    for (int j = 0; j < 4; j++) {
      bf16x8 bb = *(const bf16x8*)(bR + j * 512);
#pragma unroll
      for (int i = 0; i < 4; i++)
        acc[i][j] =
            __builtin_amdgcn_mfma_f32_16x16x32_bf16(af[i], bb, acc[i][j], 0, 0, 0);
    }
  }

  if (meta != nullptr) {
    int cnt_e = meta[e];
    int base_e = (meta + 16)[e];
#pragma unroll
    for (int i = 0; i < 4; i++) {
#pragma unroll
      for (int r = 0; r < 4; r++) {
        int s = r0 - base_e + wm * 64 + i * 16 + quad * 4 + r;
        if (s < cnt_e) {
          int tok = tlist[e * 4096 + s];
          float w = gwv[e * 4096 + s];
          float* orow = out + (size_t)tok * 1024 + n0 + wn * 64 + l15;
#pragma unroll
          for (int j = 0; j < 4; j++) unsafeAtomicAdd(orow + j * 16, w * acc[i][j][r]);
        }
      }
    }
  } else {
    // shared expert: plain store covers every output element exactly once
#pragma unroll
    for (int i = 0; i < 4; i++) {
#pragma unroll
      for (int r = 0; r < 4; r++) {
        int tok = r0 + wm * 64 + i * 16 + quad * 4 + r;
        float* orow = out + (size_t)tok * 1024 + n0 + wn * 64 + l15;
#pragma unroll
        for (int j = 0; j < 4; j++) orow[j * 16] = acc[i][j][r];
      }
    }
  }
}

// ---------------------------------------------------------------------------
extern "C" void kernel_launch(void* const* d_in, const int* in_sizes, int n_in,
                              void* d_out, int out_size, void* d_ws,
                              size_t ws_size, hipStream_t stream) {
  const float* x = (const float*)d_in[0];
  const float* rw = (const float*)d_in[1];
  const float* gw_ = (const float*)d_in[2];
  const float* uw_ = (const float*)d_in[3];
  const float* dw_ = (const float*)d_in[4];
  const float* sg = (const float*)d_in[5];
  const float* su = (const float*)d_in[6];
  const float* sd = (const float*)d_in[7];
  float* out = (float*)d_out;
  char* ws = (char*)d_ws;

  int* meta = (int*)(ws + 0);
  int* tlist = (int*)(ws + 256);
  float* gwv = (float*)(ws + 131328);
  u16* xb = (u16*)(ws + 262400);
  u16* Ag = (u16*)(ws + 8651008);
  u16* Hb = (u16*)(ws + 27525376);
  u16* Wbuf = (u16*)(ws + 103022848);

  // conversion-group size (experts per GEMM1 group); degrade if ws is small
  int ne = 4;
  if (ws_size < 170131712ULL) ne = 2;
  if (ws_size < 136577280ULL) ne = 1;
  const size_t EW = 4194304;  // elems per expert weight matrix

  zero_meta_kernel<<<1, 64, 0, stream>>>(meta);
  router_kernel<<<4096, 64, 0, stream>>>(x, rw, xb, tlist, gwv, meta);
  finalize_kernel<<<1, 64, 0, stream>>>(meta, out);
  gather_kernel<<<9216, 128, 0, stream>>>(xb, Ag, tlist, meta);

  // ---- shared expert (plain-store GEMM2 initializes all of out) ----
  conv_kernel<<<2048, 256, 0, stream>>>(sg, Wbuf, 524288);
  conv_kernel<<<2048, 256, 0, stream>>>(su, Wbuf + EW, 524288);
  gemm1_kernel<<<dim3(32, 32), 256, 0, stream>>>(xb, Wbuf, Wbuf + EW, Hb,
                                                 nullptr, 0, 0);
  conv_kernel<<<2048, 256, 0, stream>>>(sd, Wbuf, 524288);
  gemm2_kernel<<<dim3(8, 32, 1), 256, 0, stream>>>(Hb, Wbuf, out, nullptr, 0, 0,
                                                   tlist, gwv, 128);

  // ---- routed GEMM1 in groups of ne experts ----
  for (int g = 0; g < 8; g += ne) {
    conv_kernel<<<ne * 2048, 256, 0, stream>>>(gw_ + (size_t)g * EW, Wbuf,
                                               ne * 524288);
    conv_kernel<<<ne * 2048, 256, 0, stream>>>(uw_ + (size_t)g * EW,
                                               Wbuf + (size_t)ne * EW,
                                               ne * 524288);
    gemm1_kernel<<<dim3(32, 72), 256, 0, stream>>>(
        Ag, Wbuf, Wbuf + (size_t)ne * EW, Hb, meta, g, g + ne);
  }

  // ---- routed GEMM2 in groups of 2*ne experts, K split in 2 ----
  int ne2 = 2 * ne;
  if (ne2 > 8) ne2 = 8;
  for (int g = 0; g < 8; g += ne2) {
    conv_kernel<<<ne2 * 2048, 256, 0, stream>>>(dw_ + (size_t)g * EW, Wbuf,
                                                ne2 * 524288);
    gemm2_kernel<<<dim3(8, 72, 2), 256, 0, stream>>>(Hb, Wbuf, out, meta, g,
                                                     g + ne2, tlist, gwv, 64);
  }
}